// Round 17
// baseline (101.551 us; speedup 1.0000x reference)
//
#include <hip/hip_runtime.h>
#include <stdint.h>

// Problem constants
#define Bb 2
#define Tt 2048
#define DMm 1024
#define Hh 16
#define HDd 64
#define Mrows (Bb*Tt)          // 4096

typedef __attribute__((ext_vector_type(8)))  __bf16 bf16x8;
typedef __attribute__((ext_vector_type(4)))  __bf16 bf16x4;
typedef __attribute__((ext_vector_type(4)))  float  f32x4;
typedef __attribute__((ext_vector_type(16))) float  f32x16;
typedef __attribute__((ext_vector_type(4)))  unsigned int u32x4;
typedef __attribute__((ext_vector_type(2)))  unsigned int u32x2;

#define GLD16(gp, lp) __builtin_amdgcn_global_load_lds( \
    (const __attribute__((address_space(1))) unsigned int*)(gp), \
    (__attribute__((address_space(3))) unsigned int*)(lp), 16, 0, 0)

static __device__ __forceinline__ unsigned cvtpk_bf16(float lo, float hi) {
  unsigned r;
  asm("v_cvt_pk_bf16_f32 %0, %1, %2" : "=v"(r) : "v"(lo), "v"(hi));
  return r;
}
static __device__ __forceinline__ float exp2_hw(float x) {
  float r;
  asm("v_exp_f32 %0, %1" : "=v"(r) : "v"(x));
  return r;
}
static __device__ __forceinline__ float fmax3(float a, float b, float c) {
  return fmaxf(fmaxf(a, b), c);   // clang fuses to v_max3_f32
}
// cross-half reduce: validated __shfl_xor form (R3/R4).
// NOTE: permlane32_swap(u,u) with IDENTICAL operands mis-executed (R5 fail) —
// only use it with distinct values (as in the P-pack below).
// NOTE2: __launch_bounds__ min-waves arg spilled catastrophically TWICE
// (R4: cap64, R14: cap~102->alloc48, 7x slowdown). Never use it here.
// NOTE3: fp32-x staging in gemm_qkv regressed +10us (R15). Keep A in bf16.
static __device__ __forceinline__ float xmax32(float v) {
  return fmaxf(v, __shfl_xor(v, 32));
}
static __device__ __forceinline__ float xsum32(float v) {
  return v + __shfl_xor(v, 32);
}

// ---------------- fused cast fp32->bf16 (x, w_qkv, w_proj) + cs table -------
__global__ __launch_bounds__(256)
void cast3_k(const float* __restrict__ a, const float* __restrict__ b,
             const float* __restrict__ c,
             __bf16* __restrict__ oa, __bf16* __restrict__ ob,
             __bf16* __restrict__ oc,
             const float* __restrict__ cosb, const float* __restrict__ sinb,
             unsigned* __restrict__ cs) {
  const int NA = 1048576, NB = 786432, NC = 262144;   // float4 counts
  int i = blockIdx.x * 256 + threadIdx.x;
  if (i < NA + NB + NC) {
    const float* src; __bf16* dst; int k;
    if (i < NA)            { src = a; dst = oa; k = i; }
    else if (i < NA + NB)  { src = b; dst = ob; k = i - NA; }
    else                   { src = c; dst = oc; k = i - NA - NB; }
    float4 v = ((const float4*)src)[k];
    bf16x4 o;
    o[0] = (__bf16)v.x; o[1] = (__bf16)v.y; o[2] = (__bf16)v.z; o[3] = (__bf16)v.w;
    ((bf16x4*)dst)[k] = o;
  } else {
    int k = i - (NA + NB + NC);          // 0..131071
    cs[k] = cvtpk_bf16(cosb[k], sinb[k]);   // lo=cos, hi=sin
  }
}

// ---------------- GEMM2: out = attno @ wproj^T, fp32 out --------------------
// 128(M)x64(N) tiles -> 512 blocks = 2/CU. XCD-local map (validated R13).
__global__ __launch_bounds__(256)
void gemm_bt(const __bf16* __restrict__ A, const __bf16* __restrict__ Bm,
             float* __restrict__ C) {
  const int N = 1024, K = 1024;
  __shared__ __bf16 As[128 * 32];
  __shared__ __bf16 Bs[64 * 32];
  const int bid = blockIdx.x;
  const int xcd = bid & 7, i2 = bid >> 3;          // i2: 0..63
  const int rowBase = (xcd * 4 + (i2 & 3)) * 128;
  const int colBase = (i2 >> 2) * 64;
  const int tid  = threadIdx.x;
  const int lane = tid & 63, wid = tid >> 6;
  const int l4 = lane & 15, lhi = lane >> 4;
  const int wh = wid >> 1, ww = wid & 1;
  f32x4 acc[4][2] = {};
  const int e0 = wid * 512 + lane * 8;
  const int r0 = e0 >> 5, c0 = e0 & 31;
  const __bf16* a0 = A  + (size_t)(rowBase + r0)      * K + c0;
  const __bf16* a1 = A  + (size_t)(rowBase + r0 + 64) * K + c0;
  const __bf16* b0 = Bm + (size_t)(colBase + r0)      * K + c0;
  for (int k0 = 0; k0 < K; k0 += 32) {
    __syncthreads();
    GLD16(a0 + k0, &As[wid * 512]);
    GLD16(a1 + k0, &As[2048 + wid * 512]);
    GLD16(b0 + k0, &Bs[wid * 512]);
    __syncthreads();
    bf16x8 af[4], bfr[2];
#pragma unroll
    for (int i = 0; i < 4; i++)
      af[i]  = *(const bf16x8*)&As[(wh * 64 + i * 16 + l4) * 32 + lhi * 8];
#pragma unroll
    for (int j = 0; j < 2; j++)
      bfr[j] = *(const bf16x8*)&Bs[(ww * 32 + j * 16 + l4) * 32 + lhi * 8];
#pragma unroll
    for (int i = 0; i < 4; i++)
#pragma unroll
      for (int j = 0; j < 2; j++)
        acc[i][j] = __builtin_amdgcn_mfma_f32_16x16x32_bf16(af[i], bfr[j], acc[i][j], 0, 0, 0);
  }
#pragma unroll
  for (int i = 0; i < 4; i++) {
    int R = rowBase + wh * 64 + i * 16 + lhi * 4;
#pragma unroll
    for (int j = 0; j < 2; j++) {
      int Cc = colBase + ww * 32 + j * 16 + l4;
      float* cp = C + (size_t)R * N + Cc;
#pragma unroll
      for (int q = 0; q < 4; q++) cp[(size_t)q * N] = acc[i][j][q];
    }
  }
}

// ---------------- GEMM1 fused: x @ w_qkv^T -> RoPE -> fragment-major Q/K/V --
// bf16 A (R13-validated). Epilogue v2: packed bf16 cos/sin + LDS-staged
// coalesced output. XCD-local 1D map.
__global__ __launch_bounds__(256)
void gemm_qkv(const __bf16* __restrict__ A, const __bf16* __restrict__ Bm,
              __bf16* __restrict__ Qb, __bf16* __restrict__ Kb,
              __bf16* __restrict__ Vfb, const unsigned* __restrict__ csb) {
  const int K = 1024;
  __shared__ __bf16 ldsu[16384];       // 32KB: As=first 8KB, Bs=next 8KB; stage=all
  __bf16* As = ldsu;
  __bf16* Bs = ldsu + 4096;
  const int bid = blockIdx.x;
  const int xcd = bid & 7, i2 = bid >> 3;          // i2: 0..95
  const int rowBase = (xcd * 4 + (i2 & 3)) * 128;
  const int colBase = (i2 >> 2) * 128;
  const int tid  = threadIdx.x;
  const int lane = tid & 63, wid = tid >> 6;
  const int l4 = lane & 15, lhi = lane >> 4;
  const int wh = wid >> 1, ww = wid & 1;
  f32x4 acc[4][4] = {};
  const int e0 = wid * 512 + lane * 8;
  const int r0 = e0 >> 5, c0 = e0 & 31;
  const __bf16* a0 = A  + (size_t)(rowBase + r0)      * K + c0;
  const __bf16* a1 = A  + (size_t)(rowBase + r0 + 64) * K + c0;
  const __bf16* b0 = Bm + (size_t)(colBase + r0)      * K + c0;
  const __bf16* b1 = Bm + (size_t)(colBase + r0 + 64) * K + c0;
  for (int k0 = 0; k0 < K; k0 += 32) {
    __syncthreads();
    GLD16(a0 + k0, &As[wid * 512]);
    GLD16(a1 + k0, &As[2048 + wid * 512]);
    GLD16(b0 + k0, &Bs[wid * 512]);
    GLD16(b1 + k0, &Bs[2048 + wid * 512]);
    __syncthreads();
    bf16x8 af[4], bfr[4];
#pragma unroll
    for (int i = 0; i < 4; i++) {
      af[i]  = *(const bf16x8*)&As[(wh * 64 + i * 16 + l4) * 32 + lhi * 8];
      bfr[i] = *(const bf16x8*)&Bs[(ww * 64 + i * 16 + l4) * 32 + lhi * 8];
    }
#pragma unroll
    for (int i = 0; i < 4; i++)
#pragma unroll
      for (int j = 0; j < 4; j++)
        acc[i][j] = __builtin_amdgcn_mfma_f32_16x16x32_bf16(af[i], bfr[j], acc[i][j], 0, 0, 0);
  }

  // ---- fused epilogue v2 ----
  const int region = colBase >> 10;             // 0=Q, 1=K, 2=V (block-uniform)
  const int base_h = (colBase & 1023) >> 6;     // first head of this block
  const int bIdx   = rowBase >> 11;             // batch (block never straddles)
  const int tileBase = (rowBase & 2047) >> 5;   // first 32-row tile

  __syncthreads();                              // done reading As/Bs; reuse as stage

  if (region < 2) {
    const float qscale = region ? 1.f : 0.18033688f;   // 0.125*log2(e) for Q
#pragma unroll
    for (int i = 0; i < 4; i++) {
      const int tbase = ww * 8192 + (wh * 2 + (i >> 1)) * 2048;
      const int rsub  = (i & 1) * 16 + lhi * 4;          // +q -> tl&31
      const int trow0 = (rowBase & 2047) + wh * 64 + i * 16 + lhi * 4;
#pragma unroll
      for (int j = 0; j < 4; j++) {
        int dd = j * 16 + l4;
        float sg = (j < 2) ? -1.f : 1.f;
        int lbase = tbase + j * 512 + (l4 >> 3) * 256 + (l4 & 7);
#pragma unroll
        for (int q = 0; q < 4; q++) {
          unsigned cw = csb[(trow0 + q) * 64 + dd];
          float cc = __builtin_bit_cast(float, cw << 16);
          float sn = __builtin_bit_cast(float, cw & 0xffff0000u);
          float r = (acc[i][j][q] * cc + sg * acc[i][j ^ 2][q] * sn) * qscale;
          ldsu[lbase + (rsub + q) * 8] = (__bf16)r;
        }
      }
    }
  } else {
#pragma unroll
    for (int i = 0; i < 4; i++) {
      const int tbase = ww * 8192 + (wh * 2 + (i >> 1)) * 2048 + (i & 1) * 512;
#pragma unroll
      for (int j = 0; j < 4; j++) {
        int lbase = tbase + (j >> 1) * 1024 + ((j & 1) * 16 + l4) * 8;
#pragma unroll
        for (int q = 0; q < 4; q++) {
          int rq = lhi * 4 + q;                 // 0..15
          ldsu[lbase + ((rq >> 3) & 1) * 256 + (rq & 7)] = (__bf16)acc[i][j][q];
        }
      }
    }
  }
  __syncthreads();

  __bf16* dstBuf = (region == 0) ? Qb : (region == 1 ? Kb : Vfb);
#pragma unroll
  for (int h2 = 0; h2 < 2; ++h2) {
    __bf16* dst = dstBuf + (size_t)(bIdx * 16 + base_h + h2) * (Tt * 64)
                + (size_t)tileBase * 2048;
#pragma unroll
    for (int k = 0; k < 4; ++k) {
      int eoff = k * 2048 + tid * 8;
      *(bf16x8*)(dst + eoff) = *(const bf16x8*)&ldsu[h2 * 8192 + eoff];
    }
  }
}

// ---------------- Flash attention: 4-way k-split, fragment-major loads ------
// R13 structure + T15 att[2] double-pipeline: QK^T of tile t+1 (MFMA pipe)
// overlaps softmax-finish of tile t (VALU pipe). Two named score states
// sA/sB (static indexing, rule #20). +16 VGPR (104->~120), stays <=128 so
// 4 waves/SIMD preserved.
__global__ __launch_bounds__(256)
void attn_k(const __bf16* __restrict__ Q, const __bf16* __restrict__ K,
            const __bf16* __restrict__ Vb, __bf16* __restrict__ O) {
  const int bid = blockIdx.x;
  const int xcd = bid & 7;
  const int ii  = bid >> 3;
  const int bh  = xcd * 4 + (ii & 3);
  const int jj  = ii >> 2;                  // 0..31
  const int b = bh >> 4, h = bh & 15;
  const int tid = threadIdx.x, lane = tid & 63, w = tid >> 6;
  const int l5 = lane & 31, hi = lane >> 5;
  const size_t baseF = (size_t)bh * (Tt * 64);
  const int laneoff = (hi << 8) + (l5 << 3);   // hi*256 + l5*8 elems
  const float NEG_INF = -__builtin_inff();

  __shared__ float  oL[4][32][65];    // [wave][q-row][d] fp32 partials, 33.3KB
  __shared__ float2 msL[4][32];       // [wave][q-row] (m, ssum)

#define FRAGP(P, tile, c) ((P) + baseF + (size_t)(((tile) * 4 + (c)) << 9) + laneoff)

#define LOADK(KA, TIX) do {                                               \
    KA[0] = *(const bf16x8*)FRAGP(K, (TIX), 0);                           \
    KA[1] = *(const bf16x8*)FRAGP(K, (TIX), 1);                           \
    KA[2] = *(const bf16x8*)FRAGP(K, (TIX), 2);                           \
    KA[3] = *(const bf16x8*)FRAGP(K, (TIX), 3);                           \
  } while (0)
#define LOADV(TIX) do {                                                   \
    vc[0] = *(const bf16x8*)FRAGP(Vb, (TIX), 0);                          \
    vc[1] = *(const bf16x8*)FRAGP(Vb, (TIX), 1);                          \
    vc[2] = *(const bf16x8*)FRAGP(Vb, (TIX), 2);                          \
    vc[3] = *(const bf16x8*)FRAGP(Vb, (TIX), 3);                          \
  } while (0)

// QK^T for one 32-key tile -> fresh score state SREG (pure MFMA)
#define QKT(SREG, KA) do {                                                \
    SREG = (f32x16){};                                                    \
    __builtin_amdgcn_s_setprio(1);                                        \
    SREG = __builtin_amdgcn_mfma_f32_32x32x16_bf16(KA[0], qf[0], SREG, 0, 0, 0);\
    SREG = __builtin_amdgcn_mfma_f32_32x32x16_bf16(KA[1], qf[1], SREG, 0, 0, 0);\
    SREG = __builtin_amdgcn_mfma_f32_32x32x16_bf16(KA[2], qf[2], SREG, 0, 0, 0);\
    SREG = __builtin_amdgcn_mfma_f32_32x32x16_bf16(KA[3], qf[3], SREG, 0, 0, 0);\
    __builtin_amdgcn_s_setprio(0);                                        \
  } while (0)

// softmax-finish + PV for a tile whose scores are in SREG (VALU + PV MFMA)
#define FINISH(SREG, TIX) do {                                            \
    if ((TIX) == qsub) {                                                  \
      _Pragma("unroll")                                                   \
      for (int r = 0; r < 16; r++) {                                      \
        int kof = (r & 3) + 8 * (r >> 2) + 4 * hi;                        \
        SREG[r] = (kof <= l5) ? SREG[r] : NEG_INF;                        \
      }                                                                   \
    }                                                                     \
    float t0 = fmax3(SREG[0], SREG[1], SREG[2]);                          \
    float t1 = fmax3(SREG[3], SREG[4], SREG[5]);                          \
    float t2 = fmax3(SREG[6], SREG[7], SREG[8]);                          \
    float t3 = fmax3(SREG[9], SREG[10], SREG[11]);                        \
    float t4 = fmax3(SREG[12], SREG[13], SREG[14]);                       \
    float pmax = fmaxf(fmax3(t0, t1, t2), fmax3(t3, t4, SREG[15]));       \
    pmax = xmax32(pmax);                                                  \
    if (__any(pmax > m + 11.5f)) {                                        \
      float mn = fmaxf(m, pmax);                                          \
      float al = exp2_hw(m - mn);                                         \
      m = mn;                                                             \
      ssum *= al;                                                         \
      float arow[16];                                                     \
      _Pragma("unroll")                                                   \
      for (int r = 0; r < 16; r++)                                        \
        arow[r] = __shfl(al, (r & 3) + 8 * (r >> 2) + 4 * hi);            \
      _Pragma("unroll")                                                   \
      for (int r = 0; r < 16; r++) { o0[r] *= arow[r]; o1[r] *= arow[r]; }\
    }                                                                     \
    float p[16], rsl = 0.f;                                               \
    _Pragma("unroll")                                                     \
    for (int r = 0; r < 16; r++) { p[r] = exp2_hw(SREG[r] - m); rsl += p[r]; } \
    ssum += xsum32(rsl);                                                  \
    bf16x8 pa[2];                                                         \
    _Pragma("unroll")                                                     \
    for (int kc = 0; kc < 2; kc++) {                                      \
      const float* pp = p + kc * 8;                                       \
      unsigned X0 = cvtpk_bf16(pp[0], pp[1]);                             \
      unsigned Y0 = cvtpk_bf16(pp[4], pp[5]);                             \
      unsigned X1 = cvtpk_bf16(pp[2], pp[3]);                             \
      unsigned Y1 = cvtpk_bf16(pp[6], pp[7]);                             \
      u32x2 q0 = __builtin_amdgcn_permlane32_swap(X0, Y0, false, false);  \
      u32x2 q1 = __builtin_amdgcn_permlane32_swap(X1, Y1, false, false);  \
      u32x4 pw;                                                           \
      pw[0] = q0[0]; pw[1] = q1[0]; pw[2] = q0[1]; pw[3] = q1[1];         \
      pa[kc] = __builtin_bit_cast(bf16x8, pw);                            \
    }                                                                     \
    __builtin_amdgcn_s_setprio(1);                                        \
    o0 = __builtin_amdgcn_mfma_f32_32x32x16_bf16(pa[0], vc[0], o0, 0, 0, 0);\
    o0 = __builtin_amdgcn_mfma_f32_32x32x16_bf16(pa[1], vc[1], o0, 0, 0, 0);\
    o1 = __builtin_amdgcn_mfma_f32_32x32x16_bf16(pa[0], vc[2], o1, 0, 0, 0);\
    o1 = __builtin_amdgcn_mfma_f32_32x32x16_bf16(pa[1], vc[3], o1, 0, 0, 0);\
    __builtin_amdgcn_s_setprio(0);                                        \
  } while (0)

#define TCLAMP(tx) ( ((tx) > qsub) ? qsub : (tx) )

  for (int ph = 0; ph < 2; ++ph) {
    const int qsub  = ph ? (63 - jj) : jj;
    const int qrow0 = qsub * 32;

    bf16x8 qf[4];
#pragma unroll
    for (int cc = 0; cc < 4; cc++)
      qf[cc] = *(const bf16x8*)FRAGP(Q, qsub, cc);

    f32x16 o0 = {}, o1 = {};
    float m = NEG_INF, ssum = 0.f;

    const int NT = qsub + 1;                 // causal 32-key tiles
    const int dtw = NT - w;
    const int n = (dtw > 0) ? ((dtw + 3) >> 2) : 0;   // tiles for this wave

    bf16x8 kA[4], kB[4], vc[4];
    f32x16 sA, sB;

    if (n > 0) {
      // prologue: scores for tile 0 of this wave
      LOADK(kA, TCLAMP(w));
      QKT(sA, kA);
      int i = 0;
      for (; i + 2 <= n; i += 2) {
        // stage 1: QKT(t+1) overlaps FINISH(t)
        LOADV(w + 4 * i);
        LOADK(kB, TCLAMP(w + 4 * i + 4));
        QKT(sB, kB);
        FINISH(sA, w + 4 * i);
        // stage 2: QKT(t+2) overlaps FINISH(t+1)
        LOADV(w + 4 * i + 4);
        LOADK(kA, TCLAMP(w + 4 * i + 8));
        QKT(sA, kA);
        FINISH(sB, w + 4 * i + 4);
      }
      if (i < n) {               // odd tail: sA already holds tile i's scores
        LOADV(w + 4 * i);
        FINISH(sA, w + 4 * i);
      }
    }

    // ---- 4-way flash-decoding combine (fp32 partials in LDS) ----
#pragma unroll
    for (int r = 0; r < 16; r++) {
      int row = (r & 3) + 8 * (r >> 2) + 4 * hi;
      oL[w][row][l5]      = o0[r];
      oL[w][row][32 + l5] = o1[r];
    }
    if (hi == 0) msL[w][l5] = make_float2(m, ssum);
    __syncthreads();

    {
      const int row = l5;
      const int dbase = w * 16 + hi * 8;
      float2 s0 = msL[0][row], s1 = msL[1][row], s2 = msL[2][row], s3 = msL[3][row];
      float M = fmaxf(fmaxf(s0.x, s1.x), fmaxf(s2.x, s3.x));
      float a0 = exp2_hw(s0.x - M), a1 = exp2_hw(s1.x - M);
      float a2 = exp2_hw(s2.x - M), a3 = exp2_hw(s3.x - M);
      float inv = 1.f / (a0 * s0.y + a1 * s1.y + a2 * s2.y + a3 * s3.y);
      bf16x8 ov;
#pragma unroll
      for (int e = 0; e < 8; e++) {
        float v = a0 * oL[0][row][dbase + e] + a1 * oL[1][row][dbase + e]
                + a2 * oL[2][row][dbase + e] + a3 * oL[3][row][dbase + e];
        ov[e] = (__bf16)(v * inv);
      }
      *(bf16x8*)(O + ((size_t)b * Tt + qrow0 + row) * DMm + h * 64 + dbase) = ov;
    }
    __syncthreads();   // protect LDS reuse by next phase
  }
}

// ---------------- launch -----------------------------------------------------
extern "C" void kernel_launch(void* const* d_in, const int* in_sizes, int n_in,
                              void* d_out, int out_size, void* d_ws, size_t ws_size,
                              hipStream_t stream) {
  const float* x     = (const float*)d_in[0];
  const float* cosb  = (const float*)d_in[1];
  const float* sinb  = (const float*)d_in[2];
  const float* wqkv  = (const float*)d_in[3];
  const float* wproj = (const float*)d_in[4];
  float* out = (float*)d_out;

  char* ws = (char*)d_ws;
  __bf16*   xb     = (__bf16*)(ws + 0);          //  8 MB  (4096x1024)
  __bf16*   wqkvb  = (__bf16*)(ws + 8388608);    //  6 MB  (3072x1024)
  __bf16*   wprojb = (__bf16*)(ws + 14680064);   //  2 MB  (1024x1024)
  unsigned* csb    = (unsigned*)(ws + 16777216); // 512 KB packed (cos,sin) bf16
  __bf16*   Qb     = (__bf16*)(ws + 17825792);   //  8 MB  fragment-major
  __bf16*   Kb     = (__bf16*)(ws + 26214400);   //  8 MB  fragment-major
  __bf16*   Vfb    = (__bf16*)(ws + 34603008);   //  8 MB  fragment-major
  __bf16*   attno  = (__bf16*)(ws + 42991616);   //  8 MB  [B,T,1024]

  cast3_k<<<8704, 256, 0, stream>>>(x, wqkv, wproj, xb, wqkvb, wprojb,
                                    cosb, sinb, csb);

  gemm_qkv<<<768, 256, 0, stream>>>(xb, wqkvb, Qb, Kb, Vfb, csb);

  attn_k<<<1024, 256, 0, stream>>>(Qb, Kb, Vfb, attno);

  gemm_bt<<<512, 256, 0, stream>>>(attno, wprojb, out);
}

// Round 18
// 99.130 us; speedup vs baseline: 1.0244x; 1.0244x over previous
//
#include <hip/hip_runtime.h>
#include <stdint.h>

// Problem constants
#define Bb 2
#define Tt 2048
#define DMm 1024
#define Hh 16
#define HDd 64
#define Mrows (Bb*Tt)          // 4096

typedef __attribute__((ext_vector_type(8)))  __bf16 bf16x8;
typedef __attribute__((ext_vector_type(4)))  __bf16 bf16x4;
typedef __attribute__((ext_vector_type(4)))  float  f32x4;
typedef __attribute__((ext_vector_type(16))) float  f32x16;
typedef __attribute__((ext_vector_type(4)))  unsigned int u32x4;
typedef __attribute__((ext_vector_type(2)))  unsigned int u32x2;

#define GLD16(gp, lp) __builtin_amdgcn_global_load_lds( \
    (const __attribute__((address_space(1))) unsigned int*)(gp), \
    (__attribute__((address_space(3))) unsigned int*)(lp), 16, 0, 0)

static __device__ __forceinline__ unsigned cvtpk_bf16(float lo, float hi) {
  unsigned r;
  asm("v_cvt_pk_bf16_f32 %0, %1, %2" : "=v"(r) : "v"(lo), "v"(hi));
  return r;
}
static __device__ __forceinline__ float exp2_hw(float x) {
  float r;
  asm("v_exp_f32 %0, %1" : "=v"(r) : "v"(x));
  return r;
}
static __device__ __forceinline__ float fmax3(float a, float b, float c) {
  return fmaxf(fmaxf(a, b), c);   // clang fuses to v_max3_f32
}
// cross-half reduce: validated __shfl_xor form (R3/R4).
// NOTE: permlane32_swap(u,u) with IDENTICAL operands mis-executed (R5 fail) —
// only use it with distinct values (as in the P-pack below).
// NOTE2: __launch_bounds__ min-waves arg spilled catastrophically TWICE
// (R4: cap64, R14: cap~102->alloc48, 7x slowdown). Never use it here.
// NOTE3: fp32-x staging in gemm_qkv regressed +10us (R15). Keep A in bf16.
// NOTE4: T15 att[2] double-pipeline regressed +3.3us (R17) — m253 null
// confirmed: the textual QKT/FINISH interleave doesn't survive scheduling.
static __device__ __forceinline__ float xmax32(float v) {
  return fmaxf(v, __shfl_xor(v, 32));
}
static __device__ __forceinline__ float xsum32(float v) {
  return v + __shfl_xor(v, 32);
}

// ---------------- fused cast fp32->bf16 (x, w_qkv, w_proj) + cs table -------
__global__ __launch_bounds__(256)
void cast3_k(const float* __restrict__ a, const float* __restrict__ b,
             const float* __restrict__ c,
             __bf16* __restrict__ oa, __bf16* __restrict__ ob,
             __bf16* __restrict__ oc,
             const float* __restrict__ cosb, const float* __restrict__ sinb,
             unsigned* __restrict__ cs) {
  const int NA = 1048576, NB = 786432, NC = 262144;   // float4 counts
  int i = blockIdx.x * 256 + threadIdx.x;
  if (i < NA + NB + NC) {
    const float* src; __bf16* dst; int k;
    if (i < NA)            { src = a; dst = oa; k = i; }
    else if (i < NA + NB)  { src = b; dst = ob; k = i - NA; }
    else                   { src = c; dst = oc; k = i - NA - NB; }
    float4 v = ((const float4*)src)[k];
    bf16x4 o;
    o[0] = (__bf16)v.x; o[1] = (__bf16)v.y; o[2] = (__bf16)v.z; o[3] = (__bf16)v.w;
    ((bf16x4*)dst)[k] = o;
  } else {
    int k = i - (NA + NB + NC);          // 0..131071
    cs[k] = cvtpk_bf16(cosb[k], sinb[k]);   // lo=cos, hi=sin
  }
}

// ---------------- GEMM2: out = attno @ wproj^T, fp32 out --------------------
// 128(M)x64(N) tiles -> 512 blocks = 2/CU. XCD-local map (validated R13).
__global__ __launch_bounds__(256)
void gemm_bt(const __bf16* __restrict__ A, const __bf16* __restrict__ Bm,
             float* __restrict__ C) {
  const int N = 1024, K = 1024;
  __shared__ __bf16 As[128 * 32];
  __shared__ __bf16 Bs[64 * 32];
  const int bid = blockIdx.x;
  const int xcd = bid & 7, i2 = bid >> 3;          // i2: 0..63
  const int rowBase = (xcd * 4 + (i2 & 3)) * 128;
  const int colBase = (i2 >> 2) * 64;
  const int tid  = threadIdx.x;
  const int lane = tid & 63, wid = tid >> 6;
  const int l4 = lane & 15, lhi = lane >> 4;
  const int wh = wid >> 1, ww = wid & 1;
  f32x4 acc[4][2] = {};
  const int e0 = wid * 512 + lane * 8;
  const int r0 = e0 >> 5, c0 = e0 & 31;
  const __bf16* a0 = A  + (size_t)(rowBase + r0)      * K + c0;
  const __bf16* a1 = A  + (size_t)(rowBase + r0 + 64) * K + c0;
  const __bf16* b0 = Bm + (size_t)(colBase + r0)      * K + c0;
  for (int k0 = 0; k0 < K; k0 += 32) {
    __syncthreads();
    GLD16(a0 + k0, &As[wid * 512]);
    GLD16(a1 + k0, &As[2048 + wid * 512]);
    GLD16(b0 + k0, &Bs[wid * 512]);
    __syncthreads();
    bf16x8 af[4], bfr[2];
#pragma unroll
    for (int i = 0; i < 4; i++)
      af[i]  = *(const bf16x8*)&As[(wh * 64 + i * 16 + l4) * 32 + lhi * 8];
#pragma unroll
    for (int j = 0; j < 2; j++)
      bfr[j] = *(const bf16x8*)&Bs[(ww * 32 + j * 16 + l4) * 32 + lhi * 8];
#pragma unroll
    for (int i = 0; i < 4; i++)
#pragma unroll
      for (int j = 0; j < 2; j++)
        acc[i][j] = __builtin_amdgcn_mfma_f32_16x16x32_bf16(af[i], bfr[j], acc[i][j], 0, 0, 0);
  }
#pragma unroll
  for (int i = 0; i < 4; i++) {
    int R = rowBase + wh * 64 + i * 16 + lhi * 4;
#pragma unroll
    for (int j = 0; j < 2; j++) {
      int Cc = colBase + ww * 32 + j * 16 + l4;
      float* cp = C + (size_t)R * N + Cc;
#pragma unroll
      for (int q = 0; q < 4; q++) cp[(size_t)q * N] = acc[i][j][q];
    }
  }
}

// ---------------- GEMM1 fused: x @ w_qkv^T -> RoPE -> fragment-major Q/K/V --
// bf16 A (R13-validated). Epilogue v2: packed bf16 cos/sin + LDS-staged
// coalesced output. XCD-local 1D map.
__global__ __launch_bounds__(256)
void gemm_qkv(const __bf16* __restrict__ A, const __bf16* __restrict__ Bm,
              __bf16* __restrict__ Qb, __bf16* __restrict__ Kb,
              __bf16* __restrict__ Vfb, const unsigned* __restrict__ csb) {
  const int K = 1024;
  __shared__ __bf16 ldsu[16384];       // 32KB: As=first 8KB, Bs=next 8KB; stage=all
  __bf16* As = ldsu;
  __bf16* Bs = ldsu + 4096;
  const int bid = blockIdx.x;
  const int xcd = bid & 7, i2 = bid >> 3;          // i2: 0..95
  const int rowBase = (xcd * 4 + (i2 & 3)) * 128;
  const int colBase = (i2 >> 2) * 128;
  const int tid  = threadIdx.x;
  const int lane = tid & 63, wid = tid >> 6;
  const int l4 = lane & 15, lhi = lane >> 4;
  const int wh = wid >> 1, ww = wid & 1;
  f32x4 acc[4][4] = {};
  const int e0 = wid * 512 + lane * 8;
  const int r0 = e0 >> 5, c0 = e0 & 31;
  const __bf16* a0 = A  + (size_t)(rowBase + r0)      * K + c0;
  const __bf16* a1 = A  + (size_t)(rowBase + r0 + 64) * K + c0;
  const __bf16* b0 = Bm + (size_t)(colBase + r0)      * K + c0;
  const __bf16* b1 = Bm + (size_t)(colBase + r0 + 64) * K + c0;
  for (int k0 = 0; k0 < K; k0 += 32) {
    __syncthreads();
    GLD16(a0 + k0, &As[wid * 512]);
    GLD16(a1 + k0, &As[2048 + wid * 512]);
    GLD16(b0 + k0, &Bs[wid * 512]);
    GLD16(b1 + k0, &Bs[2048 + wid * 512]);
    __syncthreads();
    bf16x8 af[4], bfr[4];
#pragma unroll
    for (int i = 0; i < 4; i++) {
      af[i]  = *(const bf16x8*)&As[(wh * 64 + i * 16 + l4) * 32 + lhi * 8];
      bfr[i] = *(const bf16x8*)&Bs[(ww * 64 + i * 16 + l4) * 32 + lhi * 8];
    }
#pragma unroll
    for (int i = 0; i < 4; i++)
#pragma unroll
      for (int j = 0; j < 4; j++)
        acc[i][j] = __builtin_amdgcn_mfma_f32_16x16x32_bf16(af[i], bfr[j], acc[i][j], 0, 0, 0);
  }

  // ---- fused epilogue v2 ----
  const int region = colBase >> 10;             // 0=Q, 1=K, 2=V (block-uniform)
  const int base_h = (colBase & 1023) >> 6;     // first head of this block
  const int bIdx   = rowBase >> 11;             // batch (block never straddles)
  const int tileBase = (rowBase & 2047) >> 5;   // first 32-row tile

  __syncthreads();                              // done reading As/Bs; reuse as stage

  if (region < 2) {
    const float qscale = region ? 1.f : 0.18033688f;   // 0.125*log2(e) for Q
#pragma unroll
    for (int i = 0; i < 4; i++) {
      const int tbase = ww * 8192 + (wh * 2 + (i >> 1)) * 2048;
      const int rsub  = (i & 1) * 16 + lhi * 4;          // +q -> tl&31
      const int trow0 = (rowBase & 2047) + wh * 64 + i * 16 + lhi * 4;
#pragma unroll
      for (int j = 0; j < 4; j++) {
        int dd = j * 16 + l4;
        float sg = (j < 2) ? -1.f : 1.f;
        int lbase = tbase + j * 512 + (l4 >> 3) * 256 + (l4 & 7);
#pragma unroll
        for (int q = 0; q < 4; q++) {
          unsigned cw = csb[(trow0 + q) * 64 + dd];
          float cc = __builtin_bit_cast(float, cw << 16);
          float sn = __builtin_bit_cast(float, cw & 0xffff0000u);
          float r = (acc[i][j][q] * cc + sg * acc[i][j ^ 2][q] * sn) * qscale;
          ldsu[lbase + (rsub + q) * 8] = (__bf16)r;
        }
      }
    }
  } else {
#pragma unroll
    for (int i = 0; i < 4; i++) {
      const int tbase = ww * 8192 + (wh * 2 + (i >> 1)) * 2048 + (i & 1) * 512;
#pragma unroll
      for (int j = 0; j < 4; j++) {
        int lbase = tbase + (j >> 1) * 1024 + ((j & 1) * 16 + l4) * 8;
#pragma unroll
        for (int q = 0; q < 4; q++) {
          int rq = lhi * 4 + q;                 // 0..15
          ldsu[lbase + ((rq >> 3) & 1) * 256 + (rq & 7)] = (__bf16)acc[i][j][q];
        }
      }
    }
  }
  __syncthreads();

  __bf16* dstBuf = (region == 0) ? Qb : (region == 1 ? Kb : Vfb);
#pragma unroll
  for (int h2 = 0; h2 < 2; ++h2) {
    __bf16* dst = dstBuf + (size_t)(bIdx * 16 + base_h + h2) * (Tt * 64)
                + (size_t)tileBase * 2048;
#pragma unroll
    for (int k = 0; k < 4; ++k) {
      int eoff = k * 2048 + tid * 8;
      *(bf16x8*)(dst + eoff) = *(const bf16x8*)&ldsu[h2 * 8192 + eoff];
    }
  }
}

// ---------------- Flash attention: 4-way k-split, fragment-major loads ------
// R13-validated (40.0us): grid 1024, qsub pair {jj,63-jj}, plain
// launch_bounds(256), 34.3KB single-round combine.
__global__ __launch_bounds__(256)
void attn_k(const __bf16* __restrict__ Q, const __bf16* __restrict__ K,
            const __bf16* __restrict__ Vb, __bf16* __restrict__ O) {
  const int bid = blockIdx.x;
  const int xcd = bid & 7;
  const int ii  = bid >> 3;
  const int bh  = xcd * 4 + (ii & 3);
  const int jj  = ii >> 2;                  // 0..31
  const int b = bh >> 4, h = bh & 15;
  const int tid = threadIdx.x, lane = tid & 63, w = tid >> 6;
  const int l5 = lane & 31, hi = lane >> 5;
  const size_t baseF = (size_t)bh * (Tt * 64);
  const int laneoff = (hi << 8) + (l5 << 3);   // hi*256 + l5*8 elems
  const float NEG_INF = -__builtin_inff();

  __shared__ float  oL[4][32][65];    // [wave][q-row][d] fp32 partials, 33.3KB
  __shared__ float2 msL[4][32];       // [wave][q-row] (m, ssum)

#define FRAGP(P, tile, c) ((P) + baseF + (size_t)(((tile) * 4 + (c)) << 9) + laneoff)

#define LOADK(KA, TIX) do {                                               \
    KA[0] = *(const bf16x8*)FRAGP(K, (TIX), 0);                           \
    KA[1] = *(const bf16x8*)FRAGP(K, (TIX), 1);                           \
    KA[2] = *(const bf16x8*)FRAGP(K, (TIX), 2);                           \
    KA[3] = *(const bf16x8*)FRAGP(K, (TIX), 3);                           \
  } while (0)
#define LOADV(TIX) do {                                                   \
    vc[0] = *(const bf16x8*)FRAGP(Vb, (TIX), 0);                          \
    vc[1] = *(const bf16x8*)FRAGP(Vb, (TIX), 1);                          \
    vc[2] = *(const bf16x8*)FRAGP(Vb, (TIX), 2);                          \
    vc[3] = *(const bf16x8*)FRAGP(Vb, (TIX), 3);                          \
  } while (0)

#define COMPUTE(KA, TIX) do {                                             \
    f32x16 s = {};                                                        \
    __builtin_amdgcn_s_setprio(1);                                        \
    s = __builtin_amdgcn_mfma_f32_32x32x16_bf16(KA[0], qf[0], s, 0, 0, 0);\
    s = __builtin_amdgcn_mfma_f32_32x32x16_bf16(KA[1], qf[1], s, 0, 0, 0);\
    s = __builtin_amdgcn_mfma_f32_32x32x16_bf16(KA[2], qf[2], s, 0, 0, 0);\
    s = __builtin_amdgcn_mfma_f32_32x32x16_bf16(KA[3], qf[3], s, 0, 0, 0);\
    __builtin_amdgcn_s_setprio(0);                                        \
    if ((TIX) == qsub) {                                                  \
      _Pragma("unroll")                                                   \
      for (int r = 0; r < 16; r++) {                                      \
        int kof = (r & 3) + 8 * (r >> 2) + 4 * hi;                        \
        s[r] = (kof <= l5) ? s[r] : NEG_INF;                              \
      }                                                                   \
    }                                                                     \
    float t0 = fmax3(s[0], s[1], s[2]);                                   \
    float t1 = fmax3(s[3], s[4], s[5]);                                   \
    float t2 = fmax3(s[6], s[7], s[8]);                                   \
    float t3 = fmax3(s[9], s[10], s[11]);                                 \
    float t4 = fmax3(s[12], s[13], s[14]);                                \
    float pmax = fmaxf(fmax3(t0, t1, t2), fmax3(t3, t4, s[15]));          \
    pmax = xmax32(pmax);                                                  \
    if (__any(pmax > m + 11.5f)) {                                        \
      float mn = fmaxf(m, pmax);                                          \
      float al = exp2_hw(m - mn);                                         \
      m = mn;                                                             \
      ssum *= al;                                                         \
      float arow[16];                                                     \
      _Pragma("unroll")                                                   \
      for (int r = 0; r < 16; r++)                                        \
        arow[r] = __shfl(al, (r & 3) + 8 * (r >> 2) + 4 * hi);            \
      _Pragma("unroll")                                                   \
      for (int r = 0; r < 16; r++) { o0[r] *= arow[r]; o1[r] *= arow[r]; }\
    }                                                                     \
    float p[16], rsl = 0.f;                                               \
    _Pragma("unroll")                                                     \
    for (int r = 0; r < 16; r++) { p[r] = exp2_hw(s[r] - m); rsl += p[r]; } \
    ssum += xsum32(rsl);                                                  \
    bf16x8 pa[2];                                                         \
    _Pragma("unroll")                                                     \
    for (int kc = 0; kc < 2; kc++) {                                      \
      const float* pp = p + kc * 8;                                       \
      unsigned X0 = cvtpk_bf16(pp[0], pp[1]);                             \
      unsigned Y0 = cvtpk_bf16(pp[4], pp[5]);                             \
      unsigned X1 = cvtpk_bf16(pp[2], pp[3]);                             \
      unsigned Y1 = cvtpk_bf16(pp[6], pp[7]);                             \
      u32x2 q0 = __builtin_amdgcn_permlane32_swap(X0, Y0, false, false);  \
      u32x2 q1 = __builtin_amdgcn_permlane32_swap(X1, Y1, false, false);  \
      u32x4 pw;                                                           \
      pw[0] = q0[0]; pw[1] = q1[0]; pw[2] = q0[1]; pw[3] = q1[1];         \
      pa[kc] = __builtin_bit_cast(bf16x8, pw);                            \
    }                                                                     \
    __builtin_amdgcn_s_setprio(1);                                        \
    o0 = __builtin_amdgcn_mfma_f32_32x32x16_bf16(pa[0], vc[0], o0, 0, 0, 0);\
    o0 = __builtin_amdgcn_mfma_f32_32x32x16_bf16(pa[1], vc[1], o0, 0, 0, 0);\
    o1 = __builtin_amdgcn_mfma_f32_32x32x16_bf16(pa[0], vc[2], o1, 0, 0, 0);\
    o1 = __builtin_amdgcn_mfma_f32_32x32x16_bf16(pa[1], vc[3], o1, 0, 0, 0);\
    __builtin_amdgcn_s_setprio(0);                                        \
  } while (0)

#define TCLAMP(tx) ( ((tx) > qsub) ? qsub : (tx) )

  for (int ph = 0; ph < 2; ++ph) {
    const int qsub  = ph ? (63 - jj) : jj;
    const int qrow0 = qsub * 32;

    bf16x8 qf[4];
#pragma unroll
    for (int cc = 0; cc < 4; cc++)
      qf[cc] = *(const bf16x8*)FRAGP(Q, qsub, cc);

    f32x16 o0 = {}, o1 = {};
    float m = NEG_INF, ssum = 0.f;

    const int NT = qsub + 1;                 // causal 32-key tiles
    const int dtw = NT - w;
    const int n = (dtw > 0) ? ((dtw + 3) >> 2) : 0;   // tiles for this wave

    bf16x8 kA[4], kB[4], vc[4];

    LOADK(kA, TCLAMP(w));
    int i = 0;
    for (; i + 2 <= n; i += 2) {
      LOADV(w + 4 * i);
      LOADK(kB, TCLAMP(w + 4 * i + 4));
      COMPUTE(kA, w + 4 * i);
      LOADV(w + 4 * i + 4);
      LOADK(kA, TCLAMP(w + 4 * i + 8));
      COMPUTE(kB, w + 4 * i + 4);
    }
    if (i < n) {
      LOADV(w + 4 * i);
      COMPUTE(kA, w + 4 * i);
    }

    // ---- 4-way flash-decoding combine (fp32 partials in LDS) ----
#pragma unroll
    for (int r = 0; r < 16; r++) {
      int row = (r & 3) + 8 * (r >> 2) + 4 * hi;
      oL[w][row][l5]      = o0[r];
      oL[w][row][32 + l5] = o1[r];
    }
    if (hi == 0) msL[w][l5] = make_float2(m, ssum);
    __syncthreads();

    {
      const int row = l5;
      const int dbase = w * 16 + hi * 8;
      float2 s0 = msL[0][row], s1 = msL[1][row], s2 = msL[2][row], s3 = msL[3][row];
      float M = fmaxf(fmaxf(s0.x, s1.x), fmaxf(s2.x, s3.x));
      float a0 = exp2_hw(s0.x - M), a1 = exp2_hw(s1.x - M);
      float a2 = exp2_hw(s2.x - M), a3 = exp2_hw(s3.x - M);
      float inv = 1.f / (a0 * s0.y + a1 * s1.y + a2 * s2.y + a3 * s3.y);
      bf16x8 ov;
#pragma unroll
      for (int e = 0; e < 8; e++) {
        float v = a0 * oL[0][row][dbase + e] + a1 * oL[1][row][dbase + e]
                + a2 * oL[2][row][dbase + e] + a3 * oL[3][row][dbase + e];
        ov[e] = (__bf16)(v * inv);
      }
      *(bf16x8*)(O + ((size_t)b * Tt + qrow0 + row) * DMm + h * 64 + dbase) = ov;
    }
    __syncthreads();   // protect LDS reuse by next phase
  }
}

// ---------------- launch -----------------------------------------------------
extern "C" void kernel_launch(void* const* d_in, const int* in_sizes, int n_in,
                              void* d_out, int out_size, void* d_ws, size_t ws_size,
                              hipStream_t stream) {
  const float* x     = (const float*)d_in[0];
  const float* cosb  = (const float*)d_in[1];
  const float* sinb  = (const float*)d_in[2];
  const float* wqkv  = (const float*)d_in[3];
  const float* wproj = (const float*)d_in[4];
  float* out = (float*)d_out;

  char* ws = (char*)d_ws;
  __bf16*   xb     = (__bf16*)(ws + 0);          //  8 MB  (4096x1024)
  __bf16*   wqkvb  = (__bf16*)(ws + 8388608);    //  6 MB  (3072x1024)
  __bf16*   wprojb = (__bf16*)(ws + 14680064);   //  2 MB  (1024x1024)
  unsigned* csb    = (unsigned*)(ws + 16777216); // 512 KB packed (cos,sin) bf16
  __bf16*   Qb     = (__bf16*)(ws + 17825792);   //  8 MB  fragment-major
  __bf16*   Kb     = (__bf16*)(ws + 26214400);   //  8 MB  fragment-major
  __bf16*   Vfb    = (__bf16*)(ws + 34603008);   //  8 MB  fragment-major
  __bf16*   attno  = (__bf16*)(ws + 42991616);   //  8 MB  [B,T,1024]

  cast3_k<<<8704, 256, 0, stream>>>(x, wqkv, wproj, xb, wqkvb, wprojb,
                                    cosb, sinb, csb);

  gemm_qkv<<<768, 256, 0, stream>>>(xb, wqkvb, Qb, Kb, Vfb, csb);

  attn_k<<<1024, 256, 0, stream>>>(Qb, Kb, Vfb, attno);

  gemm_bt<<<512, 256, 0, stream>>>(attno, wprojb, out);
}